// Round 2
// baseline (136.647 us; speedup 1.0000x reference)
//
#include <hip/hip_runtime.h>

// Levenshtein edit distance, ref (512,B) x hyp (512,B), B=1024, unit costs.
// Anti-diagonal wavefront, one 64-lane wave per problem, 8 cells/lane packed
// 2-per-register in PARITY-STRIDED layout: reg p = cells {p, p+4} (lo,hi).
//
// r9 = r8 with the unavailable __builtin_amdgcn_writelane replaced by the
// compiler-managed mov+dpp token injection (same VALU cost, no asm-DPP
// hazard exposure). r8 theory (unchanged):
//  - hyp tokens are WAVE-UNIFORM -> scalar pipeline. Explicit s_load_dword
//    into SGPRs (double-buffered t/tn), one lgkmcnt(0) drain per 12-step
//    iteration. No LDS at all. Token <<16 is SALU (co-issues free).
//    (r7 had VGPR_Count=32: t[]/tn[] were folded back to per-step ds_reads
//    -> lgkm stall on the critical path each step, VALUBusy 64%.)
//  - persistent DPP staging reg vseam: lane0 keeps the 1024 bias constant
//    forever (bound_ctrl=false keeps old dest on lane0), so the i=0 seam
//    is 1 dpp instead of mov+dpp.
//
// Per-step VALU: 2 dpp + 2 alignbit + 1 mov + 4 xor + 20 pk = 29.
// Issue model: 29 x 2 cyc/step x 1023 steps ~ 59k cyc ~ 25us @2.4GHz floor.
//
// Biased relative domain (exact, r7-verified): w = v - d + 1024 in [0,1024].
//   AN = min(a1s, A1, a2s + nq - 2),  nq = (ref!=hyp) via min_u16(xor,1)
// i=0 boundary: constant 1024 via persistent vseam lane0. j=0 boundary:
// fake-init 0x3FFF (decays <=2/step -> >=14337 at end, never beats real).
// nq-2 added as 0xFFFE per lane (mod-2^16 exact; true result >= 0).

#define HLEN 512
#define BATCH 1024
#define FAKE2  0x3FFF3FFFu  // packed fake-infinity
#define SENT2  0x03FF03FFu  // packed token sentinel (real tokens < 1000)
#define BIASHI 0x04000000u  // 1024 in high half: persistent lane0 of vseam
#define ONE2   0x00010001u
#define NEG22  0xFFFEFFFEu  // -2 per 16-bit lane

// lane L gets src from lane L-1; lane 0 KEEPS OLD DEST (gfx9 DPP WAVE_SHR1,
// bound_ctrl=false, old operand tied to dest). HW-verified rounds 3-7.
__device__ __forceinline__ unsigned upd_dpp(unsigned old, unsigned src) {
  return (unsigned)__builtin_amdgcn_update_dpp((int)old, (int)src, 0x138, 0xF, 0xF, false);
}
// {hi,lo} >> 16: result = {lo: lo.hi, hi: hi.lo}
__device__ __forceinline__ unsigned algn(unsigned hi, unsigned lo) {
  return __builtin_amdgcn_alignbit(hi, lo, 16);
}
// Guaranteed single-instruction VOP3P (non-volatile: schedulable/CSE-able).
__device__ __forceinline__ unsigned pkmin(unsigned a, unsigned b) {
  unsigned d; asm("v_pk_min_u16 %0, %1, %2" : "=v"(d) : "v"(a), "v"(b)); return d;
}
__device__ __forceinline__ unsigned pkadd(unsigned a, unsigned b) {
  unsigned d; asm("v_pk_add_u16 %0, %1, %2" : "=v"(d) : "v"(a), "v"(b)); return d;
}

// One diagonal step. A2/A1/AN: unsigned[4] parity-packed diagonals.
// stok: wave-uniform SGPR token for this step (injected via mov+dpp old
// operand; s_lshl is SALU). vseam: persistent DPP staging reg. Shifted
// values: a1s[p>=1] = A1[p-1], a2s[p>=1] = A2[p-1] (pure renames);
// a2s[0] = s0c (carried a1s[0]).
#define STEP(A2, A1, AN, Q0, Q1, Q2, Q3, stok)                         \
  {                                                                    \
    vseam = upd_dpp(vseam, A1[3]); /* lane0 stays BIASHI */            \
    unsigned a1s0 = algn(A1[3], vseam);                                \
    unsigned dHT = upd_dpp((stok) << 16, Q3); /* mov+dpp */            \
    unsigned hn = algn(Q3, dHT);                                       \
    unsigned nq0 = pkmin(rt[0] ^ hn, one2);                            \
    unsigned c0  = pkadd(s0c, pkadd(nq0, neg2));                       \
    AN[0] = pkmin(pkmin(a1s0, A1[0]), c0);                             \
    unsigned nq1 = pkmin(rt[1] ^ Q0, one2);                            \
    unsigned c1  = pkadd(A2[0], pkadd(nq1, neg2));                     \
    AN[1] = pkmin(pkmin(A1[0], A1[1]), c1);                            \
    unsigned nq2 = pkmin(rt[2] ^ Q1, one2);                            \
    unsigned c2  = pkadd(A2[1], pkadd(nq2, neg2));                     \
    AN[2] = pkmin(pkmin(A1[1], A1[2]), c2);                            \
    unsigned nq3 = pkmin(rt[3] ^ Q2, one2);                            \
    unsigned c3  = pkadd(A2[2], pkadd(nq3, neg2));                     \
    AN[3] = pkmin(pkmin(A1[2], A1[3]), c3);                            \
    s0c = a1s0;                                                        \
    Q3 = hn;                                                           \
  }

__global__ void __launch_bounds__(64)
edit_distance_kernel(const int* __restrict__ ref,
                     const int* __restrict__ hyp,
                     float* __restrict__ out) {
  const int b = blockIdx.x;        // one wave (block of 64) per batch element
  const int lane = threadIdx.x;    // 0..63

  // Parity-packed static ref tokens: rt[p] = {cell lane*8+p, cell lane*8+p+4}.
  unsigned rt[4];
#pragma unroll
  for (int p = 0; p < 4; ++p) {
    unsigned lo = (unsigned)ref[(lane * 8 + p) * BATCH + b];
    unsigned hi = (unsigned)ref[(lane * 8 + p + 4) * BATCH + b];
    rt[p] = lo | (hi << 16);
  }

  // SGPR token pipeline: hyp[j*BATCH+b] is wave-uniform -> s_load_dword.
  // Offsets clamped to index 511 (clamp region only feeds j>512 garbage
  // cells — r6/r7-verified). lgkmcnt counts ONLY these loads (no LDS).
  const int* hb = hyp + b;  // uniform SGPR-pair base
  unsigned t[12], tn[12];
#pragma unroll
  for (int j = 0; j < 12; ++j) {
    unsigned off = (unsigned)j * ((unsigned)BATCH * 4u);
    asm volatile("s_load_dword %0, %1, %2" : "=s"(t[j]) : "s"(hb), "s"(off));
  }
  asm volatile("s_waitcnt lgkmcnt(0)"
               : "+s"(t[0]), "+s"(t[1]), "+s"(t[2]), "+s"(t[3]),
                 "+s"(t[4]), "+s"(t[5]), "+s"(t[6]), "+s"(t[7]),
                 "+s"(t[8]), "+s"(t[9]), "+s"(t[10]), "+s"(t[11]));

  const unsigned one2 = ONE2;
  const unsigned neg2 = NEG22;

  // Rotating parity-packed diagonal buffers.
  unsigned A[4], Bv[4], Cv[4];
#pragma unroll
  for (int p = 0; p < 4; ++p) { A[p] = FAKE2; Bv[p] = FAKE2; }
  if (lane == 0) Bv[0] = 0x3FFF0400u;  // cell 0 (lo half) on diag 1: w=1024

  // Token queue (parity-packed), all sentinels.
  unsigned q0 = SENT2, q1 = SENT2, q2 = SENT2, q3 = SENT2;

  // Persistent DPP staging register: lane0 = 1024 bias, preserved forever
  // (bound_ctrl=false keeps old dest on lane0; lanes >=1 get overwritten).
  unsigned vseam = BIASHI;

  // Carried shifted-A2 seam: shifted diag-0 (all fake, lane0 lo = 1024).
  unsigned s0c;
  vseam = upd_dpp(vseam, A[3]);
  s0c = algn(A[3], vseam);

  // 85 iterations x 12 steps = d = 2..1021.
  for (int it = 0; it < 85; ++it) {
    const int base = 12 + it * 12;  // next iter's first token index
#pragma unroll
    for (int j = 0; j < 12; ++j) {
      unsigned idx = (unsigned)(base + j);
      if (idx > (unsigned)(HLEN - 1)) idx = (unsigned)(HLEN - 1);  // SALU min
      unsigned off = idx * ((unsigned)BATCH * 4u);
      asm volatile("s_load_dword %0, %1, %2" : "=s"(tn[j]) : "s"(hb), "s"(off));
    }
    STEP(A, Bv, Cv, q0, q1, q2, q3, t[0]);
    STEP(Bv, Cv, A, q3, q0, q1, q2, t[1]);
    STEP(Cv, A, Bv, q2, q3, q0, q1, t[2]);
    STEP(A, Bv, Cv, q1, q2, q3, q0, t[3]);
    STEP(Bv, Cv, A, q0, q1, q2, q3, t[4]);
    STEP(Cv, A, Bv, q3, q0, q1, q2, t[5]);
    STEP(A, Bv, Cv, q2, q3, q0, q1, t[6]);
    STEP(Bv, Cv, A, q1, q2, q3, q0, t[7]);
    STEP(Cv, A, Bv, q0, q1, q2, q3, t[8]);
    STEP(A, Bv, Cv, q3, q0, q1, q2, t[9]);
    STEP(Bv, Cv, A, q2, q3, q0, q1, t[10]);
    STEP(Cv, A, Bv, q1, q2, q3, q0, t[11]);
    // Drain this iteration's prefetch; "+s" ties consumers to post-wait
    // values (rule #18: prevents hoisting uses above the waitcnt).
    asm volatile("s_waitcnt lgkmcnt(0)"
                 : "+s"(tn[0]), "+s"(tn[1]), "+s"(tn[2]), "+s"(tn[3]),
                   "+s"(tn[4]), "+s"(tn[5]), "+s"(tn[6]), "+s"(tn[7]),
                   "+s"(tn[8]), "+s"(tn[9]), "+s"(tn[10]), "+s"(tn[11]));
#pragma unroll
    for (int j = 0; j < 12; ++j) t[j] = tn[j];  // s_movs, scalar pipe
  }

  // Epilogue: d = 1022, 1023, 1024 (tokens all clamped -> garbage region).
  STEP(A, Bv, Cv, q0, q1, q2, q3, t[0]);
  STEP(Bv, Cv, A, q3, q0, q1, q2, t[1]);
  STEP(Cv, A, Bv, q2, q3, q0, q1, t[2]);

  // Answer: diag 1024 in Bv; cell 511 = lane 63, pair 3, HIGH half.
  // At d = 1024 = BIAS, w = v exactly.
  if (lane == 63) out[b] = (float)(Bv[3] >> 16);
}

extern "C" void kernel_launch(void* const* d_in, const int* in_sizes, int n_in,
                              void* d_out, int out_size, void* d_ws, size_t ws_size,
                              hipStream_t stream) {
  const int* ref = (const int*)d_in[0];
  const int* hyp = (const int*)d_in[1];
  float* out = (float*)d_out;
  edit_distance_kernel<<<BATCH, 64, 0, stream>>>(ref, hyp, out);
}

// Round 3
// 125.553 us; speedup vs baseline: 1.0884x; 1.0884x over previous
//
#include <hip/hip_runtime.h>

// Levenshtein edit distance, ref (512,B) x hyp (512,B), B=1024, unit costs.
// Anti-diagonal wavefront, one 64-lane wave per problem, 8 cells/lane packed
// 2-per-register in PARITY-STRIDED layout: reg p = cells {p, p+4} (lo,hi).
//
// r10: token stream moved from SMEM (r9) to VECTOR pipe with counted-vmcnt
// double-buffered prefetch. Rationale (r9 counters): clock-refit shows
// ~30 VALU/step (hand count confirmed) but ~55 stall cyc/step; SMEM is
// OUT-OF-ORDER so the per-iteration lgkmcnt(0) batch drain eats any slow
// L2/L3 return (FETCH rose to 24.6MB = K$-line thrash), and at 1 wave/SIMD
// there is no TLP to hide it. Vector loads are IN-ORDER for vmcnt (m135),
// so a 2-bank pipeline with s_waitcnt vmcnt(12) gives a hard ~700cy
// prefetch distance.
//  - global_load_short_d16_hi loads the token PRE-SHIFTED into [31:16]:
//    the dpp old operand needs tok<<16, so no v_lshl and no v_mov — the
//    load dest IS the dpp tied-old register (low-half garbage is discarded
//    by the alignbit that follows).
//  - token addr: one uniform VGPR walking +4096/token, clamped to
//    511*4096 (v_min). Clamped/garbage tokens are injected at d>=514 and
//    provably cannot influence the answer (influence needs d+511 <= 1024).
//
// Per-step VALU: 2 dpp + 2 alignbit + 4 xor + 20 pk + 2 addr = 30.
// Issue model: ~60 busy cyc/step; target elapsed ~70-80 cyc/step.
//
// Biased relative domain (exact, r7-verified): w = v - d + 1024 in [0,1024].
//   AN = min(a1s, A1, a2s + nq - 2),  nq = (ref!=hyp) via min_u16(xor,1)
// i=0 boundary: constant 1024 via persistent vseam lane0. j=0 boundary:
// fake-init 0x3FFF (decays <=2/step -> >=14337 at end, never beats real).
// nq-2 added as 0xFFFE per lane (mod-2^16 exact; true result >= 0).

#define HLEN 512
#define BATCH 1024
#define FAKE2  0x3FFF3FFFu  // packed fake-infinity
#define SENT2  0x03FF03FFu  // packed token sentinel (real tokens < 1000)
#define BIASHI 0x04000000u  // 1024 in high half: persistent lane0 of vseam
#define ONE2   0x00010001u
#define NEG22  0xFFFEFFFEu  // -2 per 16-bit lane
#define TAMAX  (511u * 4096u)  // clamped max token byte-offset (in-bounds)

// lane L gets src from lane L-1; lane 0 KEEPS OLD DEST (gfx9 DPP WAVE_SHR1,
// bound_ctrl=false, old operand tied to dest). HW-verified rounds 3-7.
__device__ __forceinline__ unsigned upd_dpp(unsigned old, unsigned src) {
  return (unsigned)__builtin_amdgcn_update_dpp((int)old, (int)src, 0x138, 0xF, 0xF, false);
}
// {hi,lo} >> 16: result = {lo: lo.hi, hi: hi.lo}
__device__ __forceinline__ unsigned algn(unsigned hi, unsigned lo) {
  return __builtin_amdgcn_alignbit(hi, lo, 16);
}
// Guaranteed single-instruction VOP3P (non-volatile: schedulable/CSE-able).
__device__ __forceinline__ unsigned pkmin(unsigned a, unsigned b) {
  unsigned d; asm("v_pk_min_u16 %0, %1, %2" : "=v"(d) : "v"(a), "v"(b)); return d;
}
__device__ __forceinline__ unsigned pkadd(unsigned a, unsigned b) {
  unsigned d; asm("v_pk_add_u16 %0, %1, %2" : "=v"(d) : "v"(a), "v"(b)); return d;
}

// One diagonal step. A2/A1/AN: unsigned[4] parity-packed diagonals.
// TREG: token register for this step — bits[31:16] hold the injected token
// (loaded by global_load_short_d16_hi); consumed in place as the dpp
// tied-old dest. vseam: persistent i=0 seam staging reg. Shifted values:
// a1s[p>=1] = A1[p-1], a2s[p>=1] = A2[p-1] (renames); a2s[0] = s0c.
#define STEP(A2, A1, AN, Q0, Q1, Q2, Q3, TREG)                         \
  {                                                                    \
    vseam = upd_dpp(vseam, A1[3]); /* lane0 stays BIASHI */            \
    unsigned a1s0 = algn(A1[3], vseam);                                \
    TREG = upd_dpp(TREG, Q3);      /* lane0 keeps loaded tok<<16 */    \
    unsigned hn = algn(Q3, TREG);                                      \
    unsigned nq0 = pkmin(rt[0] ^ hn, one2);                            \
    unsigned c0  = pkadd(s0c, pkadd(nq0, neg2));                       \
    AN[0] = pkmin(pkmin(a1s0, A1[0]), c0);                             \
    unsigned nq1 = pkmin(rt[1] ^ Q0, one2);                            \
    unsigned c1  = pkadd(A2[0], pkadd(nq1, neg2));                     \
    AN[1] = pkmin(pkmin(A1[0], A1[1]), c1);                            \
    unsigned nq2 = pkmin(rt[2] ^ Q1, one2);                            \
    unsigned c2  = pkadd(A2[1], pkadd(nq2, neg2));                     \
    AN[2] = pkmin(pkmin(A1[1], A1[2]), c2);                            \
    unsigned nq3 = pkmin(rt[3] ^ Q2, one2);                            \
    unsigned c3  = pkadd(A2[2], pkadd(nq3, neg2));                     \
    AN[3] = pkmin(pkmin(A1[2], A1[3]), c3);                            \
    s0c = a1s0;                                                        \
    Q3 = hn;                                                           \
  }

// Broadcast token load: all lanes read the SAME 2-byte token into the HIGH
// half of DST (low half garbage — discarded by algn). In-order for vmcnt.
// Addr walks +4096 (one hyp row) per token, clamped in-bounds to TAMAX.
#define TLOAD(DST)                                                     \
  {                                                                    \
    asm volatile("global_load_short_d16_hi %0, %1, %2"                 \
                 : "+v"(DST) : "v"(ta), "s"(hb2));                     \
    ta += 4096u;                                                       \
    ta = (ta < TAMAX) ? ta : TAMAX;                                    \
  }

// Wait until only the newest 12 vector loads remain outstanding (= the
// other bank's prefetch); "+v" ties make consumers data-depend on the
// post-wait values (rule #18 hoist fence, r9-proven pattern).
#define TWAIT12(T)                                                     \
  asm volatile("s_waitcnt vmcnt(12)"                                   \
               : "+v"(T[0]), "+v"(T[1]), "+v"(T[2]), "+v"(T[3]),       \
                 "+v"(T[4]), "+v"(T[5]), "+v"(T[6]), "+v"(T[7]),       \
                 "+v"(T[8]), "+v"(T[9]), "+v"(T[10]), "+v"(T[11]));
#define TWAIT0(T)                                                      \
  asm volatile("s_waitcnt vmcnt(0)"                                    \
               : "+v"(T[0]), "+v"(T[1]), "+v"(T[2]), "+v"(T[3]),       \
                 "+v"(T[4]), "+v"(T[5]), "+v"(T[6]), "+v"(T[7]),       \
                 "+v"(T[8]), "+v"(T[9]), "+v"(T[10]), "+v"(T[11]));

#define STEPS12(T)                                                     \
    STEP(A, Bv, Cv, q0, q1, q2, q3, T[0]);                             \
    STEP(Bv, Cv, A, q3, q0, q1, q2, T[1]);                             \
    STEP(Cv, A, Bv, q2, q3, q0, q1, T[2]);                             \
    STEP(A, Bv, Cv, q1, q2, q3, q0, T[3]);                             \
    STEP(Bv, Cv, A, q0, q1, q2, q3, T[4]);                             \
    STEP(Cv, A, Bv, q3, q0, q1, q2, T[5]);                             \
    STEP(A, Bv, Cv, q2, q3, q0, q1, T[6]);                             \
    STEP(Bv, Cv, A, q1, q2, q3, q0, T[7]);                             \
    STEP(Cv, A, Bv, q0, q1, q2, q3, T[8]);                             \
    STEP(A, Bv, Cv, q3, q0, q1, q2, T[9]);                             \
    STEP(Bv, Cv, A, q2, q3, q0, q1, T[10]);                            \
    STEP(Cv, A, Bv, q1, q2, q3, q0, T[11]);

__global__ void __launch_bounds__(64)
edit_distance_kernel(const int* __restrict__ ref,
                     const int* __restrict__ hyp,
                     float* __restrict__ out) {
  const int b = blockIdx.x;        // one wave (block of 64) per batch element
  const int lane = threadIdx.x;    // 0..63

  // Parity-packed static ref tokens: rt[p] = {cell lane*8+p, cell lane*8+p+4}.
  unsigned rt[4];
#pragma unroll
  for (int p = 0; p < 4; ++p) {
    unsigned lo = (unsigned)ref[(lane * 8 + p) * BATCH + b];
    unsigned hi = (unsigned)ref[(lane * 8 + p + 4) * BATCH + b];
    rt[p] = lo | (hi << 16);
  }

  // Token pipeline state: uniform byte-offset walker + SGPR base at this
  // problem's column (token j low 16 bits live at byte j*4096 + b*4, LE).
  const unsigned short* hb2 = (const unsigned short*)hyp + (unsigned)b * 2u;
  unsigned ta = 0u;
  unsigned tA[12] = {0, 0, 0, 0, 0, 0, 0, 0, 0, 0, 0, 0};
  unsigned tB[12] = {0, 0, 0, 0, 0, 0, 0, 0, 0, 0, 0, 0};

  // Prologue prefetch: bank A = tokens 0-11 (iteration 0).
#pragma unroll
  for (int j = 0; j < 12; ++j) TLOAD(tA[j]);

  const unsigned one2 = ONE2;
  const unsigned neg2 = NEG22;

  // Rotating parity-packed diagonal buffers.
  unsigned A[4], Bv[4], Cv[4];
#pragma unroll
  for (int p = 0; p < 4; ++p) { A[p] = FAKE2; Bv[p] = FAKE2; }
  if (lane == 0) Bv[0] = 0x3FFF0400u;  // cell 0 (lo half) on diag 1: w=1024

  // Token queue (parity-packed), all sentinels.
  unsigned q0 = SENT2, q1 = SENT2, q2 = SENT2, q3 = SENT2;

  // Persistent DPP staging register: lane0 = 1024 bias, preserved forever
  // (bound_ctrl=false keeps old dest on lane0; lanes >=1 get overwritten).
  unsigned vseam = BIASHI;

  // Carried shifted-A2 seam: shifted diag-0 (all fake, lane0 lo = 1024).
  unsigned s0c;
  vseam = upd_dpp(vseam, A[3]);
  s0c = algn(A[3], vseam);

  // 42 pairs x 2 x 12 steps = iterations 0..83 (d = 2..1009).
  for (int p = 0; p < 42; ++p) {
    // Body A: prefetch bank B (it=2p+1), consume bank A (it=2p).
#pragma unroll
    for (int j = 0; j < 12; ++j) TLOAD(tB[j]);
    TWAIT12(tA);
    STEPS12(tA);
    // Body B: prefetch bank A (it=2p+2), consume bank B (it=2p+1).
#pragma unroll
    for (int j = 0; j < 12; ++j) TLOAD(tA[j]);
    TWAIT12(tB);
    STEPS12(tB);
  }
  // Tail iteration 84 (d = 1010..1021): tokens all clamped/garbage-safe.
  TWAIT0(tA);
  STEPS12(tA);

  // Epilogue: d = 1022, 1023, 1024. Token regs hold junk — provably
  // irrelevant: tokens injected at step d can only influence the answer
  // cell if d + 511 <= 1024, i.e. never for d >= 514.
  STEP(A, Bv, Cv, q0, q1, q2, q3, tA[0]);
  STEP(Bv, Cv, A, q3, q0, q1, q2, tA[1]);
  STEP(Cv, A, Bv, q2, q3, q0, q1, tA[2]);

  // Answer: diag 1024 in Bv; cell 511 = lane 63, pair 3, HIGH half.
  // At d = 1024 = BIAS, w = v exactly.
  if (lane == 63) out[b] = (float)(Bv[3] >> 16);
}

extern "C" void kernel_launch(void* const* d_in, const int* in_sizes, int n_in,
                              void* d_out, int out_size, void* d_ws, size_t ws_size,
                              hipStream_t stream) {
  const int* ref = (const int*)d_in[0];
  const int* hyp = (const int*)d_in[1];
  float* out = (float*)d_out;
  edit_distance_kernel<<<BATCH, 64, 0, stream>>>(ref, hyp, out);
}

// Round 4
// 121.196 us; speedup vs baseline: 1.1275x; 1.0360x over previous
//
#include <hip/hip_runtime.h>

// Levenshtein edit distance, ref (512,B) x hyp (512,B), B=1024, unit costs.
// Anti-diagonal wavefront, one 64-lane wave per problem, 8 cells/lane packed
// 2-per-register in PARITY-STRIDED layout: reg p = cells {p, p+4} (lo,hi).
//
// r11: three changes driven by r10 counters (60 busy cyc/step = exactly my
// 30-instr hand count; ~39 stall cyc/step = scheduler clustering dependent
// opaque-asm pk ops, ~2 cyc per dependent pair at 1 wave/SIMD):
//  1. Hand-scheduled asm blocks per step: breadth-first interleave of the 4
//     independent per-pair chains; every dependent pair >=3 instrs apart.
//     DPPs remain builtins (compiler inserts their hazard wait-states).
//     AN[3] is produced 3 instrs before block end -> next step's DPP that
//     reads it has >=2 wait-state slots (gfx9 VALU-write->DPP-read hazard).
//  2. Tokens injected at d>=514 cannot influence the answer (token entering
//     at cell 0 on step d reaches cell 511 at step d+511 > 1024). So token
//     loads exist only for iterations 0..42; iterations 43..84 (504 steps,
//     HALF the kernel) run with no loads/waits/addressing at all.
//  3. Token address walk on SALU (uniform pointer += 4096); the it-42 bank
//     clamps to token 511 at COMPILE time (frozen-pointer loads).
//
// Per-step VALU: 2 dpp + 2 alignbit + 4 xor + 20 pk = 28 -> 56 busy cyc.
//
// Biased relative domain (exact, r7-verified): w = v - d + 1024 in [0,1024].
//   AN = min(a1s, A1, a2s + nq - 2),  nq = (ref!=hyp) via min_u16(xor,1)
// i=0 boundary: constant 1024 via persistent vseam lane0. j=0 boundary:
// fake-init 0x3FFF (decays <=2/step -> >=14337 at end, never beats real).
// nq-2 added as 0xFFFE per lane (mod-2^16 exact; true result >= 0).

#define HLEN 512
#define BATCH 1024
#define FAKE2  0x3FFF3FFFu  // packed fake-infinity
#define SENT2  0x03FF03FFu  // packed token sentinel (real tokens < 1000)
#define BIASHI 0x04000000u  // 1024 in high half: persistent lane0 of vseam
#define ONE2   0x00010001u
#define NEG22  0xFFFEFFFEu  // -2 per 16-bit lane

// lane L gets src from lane L-1; lane 0 KEEPS OLD DEST (gfx9 DPP WAVE_SHR1,
// bound_ctrl=false, old operand tied to dest). HW-verified rounds 3-7.
__device__ __forceinline__ unsigned upd_dpp(unsigned old, unsigned src) {
  return (unsigned)__builtin_amdgcn_update_dpp((int)old, (int)src, 0x138, 0xF, 0xF, false);
}

// One diagonal step. A2/A1/AN: unsigned[4] parity-packed diagonals.
// TREG: token reg — bits[31:16] = injected token (global_load_short_d16_hi
// dest), consumed in place as the dpp tied-old. Hand-scheduled asm:
// dependent ops kept >=3 instructions apart (>=6 cyc > ~4 cyc VALU latency).
#define STEP(A2, A1, AN, Q0, Q1, Q2, Q3, TREG)                          \
  do {                                                                  \
    unsigned t0, t1, t2, t3, m0, m1, m2, m3, a1s0, hn;                  \
    vseam = upd_dpp(vseam, A1[3]); /* lane0 stays BIASHI */             \
    TREG = upd_dpp(TREG, Q3);      /* lane0 keeps loaded tok<<16 */     \
    asm("v_xor_b32 %[t1], %[rt1], %[q0]\n\t"                            \
        "v_xor_b32 %[t2], %[rt2], %[q1]\n\t"                            \
        "v_xor_b32 %[t3], %[rt3], %[q2]\n\t"                            \
        "v_alignbit_b32 %[a1s0], %[a13], %[vs], 16\n\t"                 \
        "v_alignbit_b32 %[hn], %[q3], %[tq], 16\n\t"                    \
        : [t1]"=&v"(t1), [t2]"=&v"(t2), [t3]"=&v"(t3),                  \
          [a1s0]"=&v"(a1s0), [hn]"=&v"(hn)                              \
        : [rt1]"v"(rt[1]), [rt2]"v"(rt[2]), [rt3]"v"(rt[3]),            \
          [q0]"v"(Q0), [q1]"v"(Q1), [q2]"v"(Q2), [q3]"v"(Q3),           \
          [a13]"v"(A1[3]), [vs]"v"(vseam), [tq]"v"(TREG));              \
    asm("v_pk_min_u16 %[t1], %[t1], %[one]\n\t"                         \
        "v_pk_min_u16 %[t2], %[t2], %[one]\n\t"                         \
        "v_xor_b32    %[t0], %[rt0], %[hn]\n\t"                         \
        "v_pk_min_u16 %[t3], %[t3], %[one]\n\t"                         \
        "v_pk_add_u16 %[t1], %[t1], %[neg2]\n\t"                        \
        "v_pk_min_u16 %[t0], %[t0], %[one]\n\t"                         \
        "v_pk_add_u16 %[t2], %[t2], %[neg2]\n\t"                        \
        "v_pk_add_u16 %[t3], %[t3], %[neg2]\n\t"                        \
        "v_pk_add_u16 %[t1], %[t1], %[a20]\n\t"                         \
        "v_pk_add_u16 %[t0], %[t0], %[neg2]\n\t"                        \
        "v_pk_min_u16 %[m3], %[a12], %[a13]\n\t"                        \
        "v_pk_min_u16 %[m1], %[a10], %[a11]\n\t"                        \
        "v_pk_add_u16 %[t2], %[t2], %[a21]\n\t"                         \
        "v_pk_add_u16 %[t3], %[t3], %[a22]\n\t"                         \
        "v_pk_add_u16 %[t0], %[t0], %[s0c]\n\t"                         \
        "v_pk_min_u16 %[m2], %[a11], %[a12]\n\t"                        \
        "v_pk_min_u16 %[m0], %[a1s0], %[a10]\n\t"                       \
        "v_pk_min_u16 %[t3], %[m3], %[t3]\n\t"                          \
        "v_pk_min_u16 %[t1], %[m1], %[t1]\n\t"                          \
        "v_pk_min_u16 %[t2], %[m2], %[t2]\n\t"                          \
        "v_pk_min_u16 %[t0], %[m0], %[t0]\n\t"                          \
        : [t0]"=&v"(t0), [t1]"+v"(t1), [t2]"+v"(t2), [t3]"+v"(t3),      \
          [m0]"=&v"(m0), [m1]"=&v"(m1), [m2]"=&v"(m2), [m3]"=&v"(m3)    \
        : [hn]"v"(hn), [a1s0]"v"(a1s0),                                 \
          [a10]"v"(A1[0]), [a11]"v"(A1[1]), [a12]"v"(A1[2]),            \
          [a13]"v"(A1[3]),                                              \
          [a20]"v"(A2[0]), [a21]"v"(A2[1]), [a22]"v"(A2[2]),            \
          [rt0]"v"(rt[0]), [one]"v"(one2), [neg2]"v"(neg2),             \
          [s0c]"v"(s0c));                                               \
    AN[0] = t0; AN[1] = t1; AN[2] = t2; AN[3] = t3;                     \
    s0c = a1s0;                                                         \
    Q3 = hn;                                                            \
  } while (0)

// Broadcast token load: all lanes read the SAME 2 bytes into the HIGH half
// of DST (low half preserved/garbage — discarded by the alignbit). Address
// is wave-uniform: SGPR-pair base advanced on the SCALAR pipe (+4096 B/row).
#define TLOAD(DST) do {                                                \
    asm volatile("global_load_short_d16_hi %0, %1, %2"                 \
                 : "+v"(DST) : "v"(vz), "s"(hb2));                     \
    hb2 += 2048; /* +4096 bytes, uniform -> s_add/s_addc */            \
  } while (0)
// Frozen variant: load without advancing (compile-time clamp to token 511).
#define TLOADF(DST) do {                                               \
    asm volatile("global_load_short_d16_hi %0, %1, %2"                 \
                 : "+v"(DST) : "v"(vz), "s"(hb2));                     \
  } while (0)

// Counted waits tied to the consumed bank (rule #18 hoist fence).
#define TWAIT12(T)                                                     \
  asm volatile("s_waitcnt vmcnt(12)"                                   \
               : "+v"(T[0]), "+v"(T[1]), "+v"(T[2]), "+v"(T[3]),       \
                 "+v"(T[4]), "+v"(T[5]), "+v"(T[6]), "+v"(T[7]),       \
                 "+v"(T[8]), "+v"(T[9]), "+v"(T[10]), "+v"(T[11]));
#define TWAIT0(T)                                                      \
  asm volatile("s_waitcnt vmcnt(0)"                                    \
               : "+v"(T[0]), "+v"(T[1]), "+v"(T[2]), "+v"(T[3]),       \
                 "+v"(T[4]), "+v"(T[5]), "+v"(T[6]), "+v"(T[7]),       \
                 "+v"(T[8]), "+v"(T[9]), "+v"(T[10]), "+v"(T[11]));

#define STEPS12(T)                                                     \
    STEP(A, Bv, Cv, q0, q1, q2, q3, T[0]);                             \
    STEP(Bv, Cv, A, q3, q0, q1, q2, T[1]);                             \
    STEP(Cv, A, Bv, q2, q3, q0, q1, T[2]);                             \
    STEP(A, Bv, Cv, q1, q2, q3, q0, T[3]);                             \
    STEP(Bv, Cv, A, q0, q1, q2, q3, T[4]);                             \
    STEP(Cv, A, Bv, q3, q0, q1, q2, T[5]);                             \
    STEP(A, Bv, Cv, q2, q3, q0, q1, T[6]);                             \
    STEP(Bv, Cv, A, q1, q2, q3, q0, T[7]);                             \
    STEP(Cv, A, Bv, q0, q1, q2, q3, T[8]);                             \
    STEP(A, Bv, Cv, q3, q0, q1, q2, T[9]);                             \
    STEP(Bv, Cv, A, q2, q3, q0, q1, T[10]);                            \
    STEP(Cv, A, Bv, q1, q2, q3, q0, T[11]);

__global__ void __launch_bounds__(64)
edit_distance_kernel(const int* __restrict__ ref,
                     const int* __restrict__ hyp,
                     float* __restrict__ out) {
  const int b = blockIdx.x;        // one wave (block of 64) per batch element
  const int lane = threadIdx.x;    // 0..63

  // Parity-packed static ref tokens: rt[p] = {cell lane*8+p, cell lane*8+p+4}.
  unsigned rt[4];
#pragma unroll
  for (int p = 0; p < 4; ++p) {
    unsigned lo = (unsigned)ref[(lane * 8 + p) * BATCH + b];
    unsigned hi = (unsigned)ref[(lane * 8 + p + 4) * BATCH + b];
    rt[p] = lo | (hi << 16);
  }

  // Uniform token pointer at this problem's column (token j's low 16 bits
  // live at byte j*4096 + b*4, little-endian). Advanced on the scalar pipe.
  const unsigned short* hb2 = (const unsigned short*)hyp + (unsigned)b * 2u;
  unsigned vz;
  asm("v_mov_b32 %0, 0" : "=v"(vz));  // constant-zero VGPR offset

  unsigned tA[12] = {0,0,0,0,0,0,0,0,0,0,0,0};
  unsigned tB[12] = {0,0,0,0,0,0,0,0,0,0,0,0};

  // Prologue prefetch: bank A = tokens 0-11 (iteration 0).
#pragma unroll
  for (int j = 0; j < 12; ++j) TLOAD(tA[j]);

  const unsigned one2 = ONE2;
  const unsigned neg2 = NEG22;

  // Rotating parity-packed diagonal buffers.
  unsigned A[4], Bv[4], Cv[4];
#pragma unroll
  for (int p = 0; p < 4; ++p) { A[p] = FAKE2; Bv[p] = FAKE2; }
  if (lane == 0) Bv[0] = 0x3FFF0400u;  // cell 0 (lo half) on diag 1: w=1024

  // Token queue (parity-packed), all sentinels.
  unsigned q0 = SENT2, q1 = SENT2, q2 = SENT2, q3 = SENT2;

  // Persistent DPP staging register: lane0 = 1024 bias, preserved forever
  // (bound_ctrl=false keeps old dest on lane0; lanes >=1 get overwritten).
  unsigned vseam = BIASHI;

  // Carried shifted-A2 seam: shifted diag-0 (all fake, lane0 lo = 1024).
  unsigned s0c;
  vseam = upd_dpp(vseam, A[3]);
  s0c = __builtin_amdgcn_alignbit(A[3], vseam, 16);

  // ---- Token phase: iterations 0..42 (d = 2..517), double-buffered. ----
#pragma clang loop unroll(disable)
  for (int p = 0; p < 20; ++p) {
    // Body A: prefetch bank B (it=2p+1), consume bank A (it=2p).
#pragma unroll
    for (int j = 0; j < 12; ++j) TLOAD(tB[j]);
    TWAIT12(tA);
    STEPS12(tA);
    // Body B: prefetch bank A (it=2p+2), consume bank B (it=2p+1).
#pragma unroll
    for (int j = 0; j < 12; ++j) TLOAD(tA[j]);
    TWAIT12(tB);
    STEPS12(tB);
  }
  // it=40 in bank A. Load it=41 (tokens 492-503), consume it=40.
#pragma unroll
  for (int j = 0; j < 12; ++j) TLOAD(tB[j]);
  TWAIT12(tA);
  STEPS12(tA);
  // Load it=42: tokens 504-510 advancing, then frozen at 511 (j=7..11;
  // j>=8 inject at d>=514 = provably irrelevant, j=7 needs real 511).
#pragma unroll
  for (int j = 0; j < 7; ++j) TLOAD(tA[j]);
#pragma unroll
  for (int j = 7; j < 12; ++j) TLOADF(tA[j]);
  TWAIT12(tB);
  STEPS12(tB);   // it=41
  TWAIT0(tA);
  STEPS12(tA);   // it=42 (d = 506..517)

  // ---- Load-free phase: iterations 43..84 (d = 518..1021). Token regs
  // hold shifted junk; tokens injected at d>=518 cannot influence the
  // answer (need d+511 <= 1024). Queue keeps shifting real old tokens. ----
#pragma clang loop unroll(disable)
  for (int i = 0; i < 42; ++i) {
    STEPS12(tA);
  }

  // Epilogue: d = 1022, 1023, 1024 (garbage-region injections).
  STEP(A, Bv, Cv, q0, q1, q2, q3, tA[0]);
  STEP(Bv, Cv, A, q3, q0, q1, q2, tA[1]);
  STEP(Cv, A, Bv, q2, q3, q0, q1, tA[2]);

  // Answer: diag 1024 in Bv; cell 511 = lane 63, pair 3, HIGH half.
  // At d = 1024 = BIAS, w = v exactly.
  if (lane == 63) out[b] = (float)(Bv[3] >> 16);
}

extern "C" void kernel_launch(void* const* d_in, const int* in_sizes, int n_in,
                              void* d_out, int out_size, void* d_ws, size_t ws_size,
                              hipStream_t stream) {
  const int* ref = (const int*)d_in[0];
  const int* hyp = (const int*)d_in[1];
  float* out = (float*)d_out;
  edit_distance_kernel<<<BATCH, 64, 0, stream>>>(ref, hyp, out);
}